// Round 3
// baseline (28.228 us; speedup 1.0000x reference)
//
#include <hip/hip_runtime.h>
#include <hip/hip_bf16.h>

typedef __bf16 bf16x8 __attribute__((ext_vector_type(8)));
typedef float f32x4 __attribute__((ext_vector_type(4)));

#define BATCH 2048
#define NEGS 512
#define IN_DIM 256
#define NGATE 384          // 6 * 64
#define EMB_LD 72          // padded bf16 row stride: b128 ops hit the 8-slot floor, no extra conflicts
#define TAB_LD 33          // bf16 table row stride

__device__ inline bf16x8 cvt8(float4 f0, float4 f1) {
    bf16x8 r;
    r[0] = (__bf16)f0.x; r[1] = (__bf16)f0.y; r[2] = (__bf16)f0.z; r[3] = (__bf16)f0.w;
    r[4] = (__bf16)f1.x; r[5] = (__bf16)f1.y; r[6] = (__bf16)f1.z; r[7] = (__bf16)f1.w;
    return r;
}

// ---------------- Kernel 1: g[b][p*64+d] = tanh(x[b,:] . gate_w[p,d,:] + gate_b[p,d]) -> bf16
// M=2048, N=384, K=256. One 16x16 tile per wave; unroll-2 k-loop keeps VGPR low so
// __launch_bounds__(256,4) holds 16 waves/CU for load-latency hiding.
__global__ __launch_bounds__(256, 4) void gate_gemm_kernel(
    const float* __restrict__ x, const float* __restrict__ gw,
    const float* __restrict__ gb, __bf16* __restrict__ g)
{
    const int w = threadIdx.x >> 6, l = threadIdx.x & 63;
    const int lm = l & 15, lq = l >> 4;
    const int tile = blockIdx.x * 4 + w;      // 0..3071
    const int mt = tile / 24, nt = tile % 24; // block's 4 waves share x rows (L2/L1)
    const int m0 = mt * 16, n0 = nt * 16;

    const float* xp = x + (size_t)(m0 + lm) * IN_DIM + lq * 8;
    const float* wp = gw + (size_t)(n0 + lm) * IN_DIM + lq * 8;
    f32x4 acc = {};
#pragma unroll 2
    for (int s = 0; s < 8; ++s) {
        bf16x8 a = cvt8(*(const float4*)(xp + s * 32), *(const float4*)(xp + s * 32 + 4));
        bf16x8 b = cvt8(*(const float4*)(wp + s * 32), *(const float4*)(wp + s * 32 + 4));
        acc = __builtin_amdgcn_mfma_f32_16x16x32_bf16(a, b, acc, 0, 0, 0);
    }
    // C/D layout: col = lane&15, row = (lane>>4)*4 + reg
    const int col = n0 + lm;
    const float bias = gb[col];
#pragma unroll
    for (int r = 0; r < 4; ++r) {
        const int row = m0 + lq * 4 + r;
        g[(size_t)row * NGATE + col] = (__bf16)tanhf(acc[r] + bias);
    }
}

// ---------------- Kernel 2: per-b pair tables via MFMA, then table-lookup scoring -------------
// One b per block: LDS = 23040 (emb) + 12672 (6 tables) = 35712 B -> 4 blocks/CU = 16 waves/CU.
// emb rows (sorted heads): cf_perm=0, cf_primary=1, cf_secondary=2, predictor=3, reorder=4
// label cols: predictor=0, cf_perm=1, cf_primary=2, cf_secondary=3, reorder=4 (5 unused)
// pairs p: a-head = pred(p<3)/reorder(p>=3), c-head = p%3
__global__ __launch_bounds__(256, 4) void table_score_kernel(
    const int* __restrict__ labels, const float* __restrict__ emb,
    const __bf16* __restrict__ g, float* __restrict__ out)
{
    __shared__ __align__(16) __bf16 embs[5 * 32 * EMB_LD];  // 23040 B
    __shared__ __align__(16) __bf16 tab[6 * 32 * TAB_LD];   // 12672 B

    const int t = threadIdx.x;
    const int b = blockIdx.x;
    const int w = t >> 6, l = t & 63;
    const int lm = l & 15, lq = l >> 4;

    // ---- prefetch this thread's labels (negs 2t, 2t+1): HBM latency hides under staging+build
    const int4* lp = (const int4*)(labels + (size_t)b * NEGS * 6) + 3 * t;
    const int4 q0 = lp[0];   // negA: cols 0..3
    const int4 q1 = lp[1];   // negA: col4, col5 | negB: col0, col1
    const int4 q2 = lp[2];   // negB: cols 2..5

    // ---- stage emb: f32 global (L2-hot, 40 KB) -> bf16 LDS (padded) ----
#pragma unroll
    for (int c = 0; c < 5; ++c) {
        const int j = t + c * 256;           // 1280 chunks of 8 elems
        const int head = j >> 8;
        const int rem = j & 255;
        const int v = rem >> 3, qq = rem & 7;
        const float4* src = (const float4*)(emb + (size_t)j * 8);
        bf16x8 val = cvt8(src[0], src[1]);
        *(bf16x8*)&embs[head * (32 * EMB_LD) + v * EMB_LD + qq * 8] = val;
    }
    __syncthreads();

    // ---- build 6 tables: wave w -> {w} then {w+4} for w<2 ----
    for (int id = w; id < 6; id += 4) {
        const int p = id;
        const int arow = (p < 3) ? 3 : 4;     // predictor / reorder
        const int crow = (p < 3) ? p : p - 3; // cf_perm / cf_primary / cf_secondary

        const __bf16* gp = g + (size_t)b * NGATE + p * 64 + lq * 8;
        const bf16x8 gva = *(const bf16x8*)gp;
        const bf16x8 gvb = *(const bf16x8*)(gp + 32);
        f32x4 acc[2][2] = {};

#pragma unroll
        for (int s = 0; s < 2; ++s) {
            const int k0 = s * 32 + lq * 8;
            const bf16x8 gs = s ? gvb : gva;
            float gf[8];
#pragma unroll
            for (int i = 0; i < 8; ++i) gf[i] = (float)gs[i];

            bf16x8 bfr[2], afr[2];
#pragma unroll
            for (int nh = 0; nh < 2; ++nh)
                bfr[nh] = *(const bf16x8*)&embs[crow * (32 * EMB_LD) + (nh * 16 + lm) * EMB_LD + k0];
#pragma unroll
            for (int mh = 0; mh < 2; ++mh) {
                bf16x8 ea = *(const bf16x8*)&embs[arow * (32 * EMB_LD) + (mh * 16 + lm) * EMB_LD + k0];
                bf16x8 r;
#pragma unroll
                for (int i = 0; i < 8; ++i) r[i] = (__bf16)((float)ea[i] * gf[i]);
                afr[mh] = r;
            }
#pragma unroll
            for (int mh = 0; mh < 2; ++mh)
#pragma unroll
                for (int nh = 0; nh < 2; ++nh)
                    acc[mh][nh] = __builtin_amdgcn_mfma_f32_16x16x32_bf16(afr[mh], bfr[nh], acc[mh][nh], 0, 0, 0);
        }

        __bf16* tb = tab + id * (32 * TAB_LD);
#pragma unroll
        for (int mh = 0; mh < 2; ++mh)
#pragma unroll
            for (int nh = 0; nh < 2; ++nh) {
                const int col = nh * 16 + lm;
#pragma unroll
                for (int r = 0; r < 4; ++r)
                    tb[(mh * 16 + lq * 4 + r) * TAB_LD + col] = (__bf16)acc[mh][nh][r];
            }
    }
    __syncthreads();

    // ---- score negs 2t, 2t+1 (labels already in regs) ----
    const float sA =
        (float)tab[0 * 32 * TAB_LD + q0.x * TAB_LD + q0.y] +
        (float)tab[1 * 32 * TAB_LD + q0.x * TAB_LD + q0.z] +
        (float)tab[2 * 32 * TAB_LD + q0.x * TAB_LD + q0.w] +
        (float)tab[3 * 32 * TAB_LD + q1.x * TAB_LD + q0.y] +
        (float)tab[4 * 32 * TAB_LD + q1.x * TAB_LD + q0.z] +
        (float)tab[5 * 32 * TAB_LD + q1.x * TAB_LD + q0.w];
    const float sB =
        (float)tab[0 * 32 * TAB_LD + q1.z * TAB_LD + q1.w] +
        (float)tab[1 * 32 * TAB_LD + q1.z * TAB_LD + q2.x] +
        (float)tab[2 * 32 * TAB_LD + q1.z * TAB_LD + q2.y] +
        (float)tab[3 * 32 * TAB_LD + q2.z * TAB_LD + q1.w] +
        (float)tab[4 * 32 * TAB_LD + q2.z * TAB_LD + q2.x] +
        (float)tab[5 * 32 * TAB_LD + q2.z * TAB_LD + q2.y];

    float2 res; res.x = sA; res.y = sB;
    *(float2*)(out + (size_t)b * NEGS + 2 * t) = res;
}

extern "C" void kernel_launch(void* const* d_in, const int* in_sizes, int n_in,
                              void* d_out, int out_size, void* d_ws, size_t ws_size,
                              hipStream_t stream) {
    const float* x      = (const float*)d_in[0];
    const int*   labels = (const int*)d_in[1];
    const float* emb    = (const float*)d_in[2];
    const float* gw     = (const float*)d_in[3];
    const float* gb     = (const float*)d_in[4];
    float* out = (float*)d_out;
    __bf16* g  = (__bf16*)d_ws;   // 2048*384 bf16 = 1.5 MB

    hipLaunchKernelGGL(gate_gemm_kernel, dim3(768), dim3(256), 0, stream, x, gw, gb, g);
    hipLaunchKernelGGL(table_score_kernel, dim3(BATCH), dim3(256), 0, stream,
                       labels, emb, g, out);
}